// Round 1
// baseline (460.663 us; speedup 1.0000x reference)
//
#include <hip/hip_runtime.h>

#define NN   1024
#define BB   4
#define TT   12
#define CC   64
#define DD   64
#define HH   2
#define KK   3
#define ETOT 17408           // E (16384) + N self loops
#define BT   48              // B*T
#define BTH  96              // B*T*H
#define HD   128             // H*D

// ---------------- Pass A: feat = x @ fc_w, plus el/er dot products ----------
__global__ __launch_bounds__(128) void feat_kernel(
    const float* __restrict__ x,       // [B,N,T,C]
    const float* __restrict__ fc_w,    // [K,C,HD]
    const float* __restrict__ attn_l,  // [K,H,D]
    const float* __restrict__ attn_r,  // [K,H,D]
    float* __restrict__ feat,          // [K,N,BT,HD]
    float* __restrict__ el,            // [K,N,BTH]
    float* __restrict__ er)            // [K,N,BTH]
{
    int k = blockIdx.x / NN;
    int n = blockIdx.x % NN;
    int e = threadIdx.x;          // 0..127  (= h*64 + d)
    int h = e >> 6, d = e & 63;

    __shared__ float w_lds[CC * HD];   // 32 KB
    __shared__ float x_lds[BT * CC];   // 12 KB

    for (int i = e; i < CC * HD; i += 128) w_lds[i] = fc_w[k * CC * HD + i];
    for (int i = e; i < BT * CC; i += 128) {
        int bt = i >> 6, c = i & 63;
        int b = bt / TT, t = bt - b * TT;
        x_lds[i] = x[(((size_t)b * NN + n) * TT + t) * CC + c];
    }
    __syncthreads();

    float al = attn_l[k * HD + e];
    float ar = attn_r[k * HD + e];

    for (int bt = 0; bt < BT; ++bt) {
        float f = 0.f;
        const float* xr = &x_lds[bt * CC];
        #pragma unroll
        for (int c = 0; c < CC; ++c) f = fmaf(xr[c], w_lds[c * HD + e], f);
        feat[(((size_t)(k * NN + n)) * BT + bt) * HD + e] = f;

        float pl = f * al, pr = f * ar;
        #pragma unroll
        for (int off = 32; off > 0; off >>= 1) {
            pl += __shfl_down(pl, off, 64);
            pr += __shfl_down(pr, off, 64);
        }
        if (d == 0) {
            el[(k * NN + n) * BTH + bt * HH + h] = pl;
            er[(k * NN + n) * BTH + bt * HH + h] = pr;
        }
    }
}

// ---------------- CSR build -------------------------------------------------
__global__ void count_kernel(const int* __restrict__ dst_idx, int* __restrict__ counts)
{
    int tid = blockIdx.x * blockDim.x + threadIdx.x;
    if (tid < KK * ETOT) {
        int k = tid / ETOT;
        atomicAdd(&counts[k * NN + dst_idx[tid]], 1);
    }
}

__global__ __launch_bounds__(1024) void scan_kernel(
    const int* __restrict__ counts, int* __restrict__ row_start, int* __restrict__ cursor)
{
    int k = blockIdx.x;
    int n = threadIdx.x;               // 1024 threads
    __shared__ int buf[NN];
    int my = counts[k * NN + n];
    buf[n] = my;
    __syncthreads();
    for (int off = 1; off < NN; off <<= 1) {
        int v = (n >= off) ? buf[n - off] : 0;
        __syncthreads();
        buf[n] += v;
        __syncthreads();
    }
    int incl = buf[n];
    int excl = incl - my;
    row_start[k * (NN + 1) + n] = excl;
    cursor[k * NN + n] = excl;
    if (n == NN - 1) row_start[k * (NN + 1) + NN] = incl;
}

__global__ void scatter_kernel(const int* __restrict__ src_idx,
                               const int* __restrict__ dst_idx,
                               int* __restrict__ cursor, int* __restrict__ csr_src)
{
    int tid = blockIdx.x * blockDim.x + threadIdx.x;
    if (tid < KK * ETOT) {
        int k = tid / ETOT;
        int pos = atomicAdd(&cursor[k * NN + dst_idx[tid]], 1);
        csr_src[k * ETOT + pos] = src_idx[tid];
    }
}

// ---------------- Pass C: segment softmax stats -----------------------------
__global__ __launch_bounds__(128) void attn_kernel(
    const float* __restrict__ el, const float* __restrict__ er,
    const int* __restrict__ row_start, const int* __restrict__ csr_src,
    float* __restrict__ emax, float* __restrict__ inv_denom)
{
    int k = blockIdx.x / NN, n = blockIdx.x % NN;
    int bth = threadIdx.x;
    if (bth >= BTH) return;
    int s0 = row_start[k * (NN + 1) + n];
    int s1 = row_start[k * (NN + 1) + n + 1];
    float erv = er[(k * NN + n) * BTH + bth];

    float m = -1e30f;
    for (int j = s0; j < s1; ++j) {
        int src = csr_src[k * ETOT + j];
        float ev = el[(k * NN + src) * BTH + bth] + erv;
        ev = ev > 0.f ? ev : ev * 0.2f;
        m = fmaxf(m, ev);
    }
    float s = 0.f;
    for (int j = s0; j < s1; ++j) {
        int src = csr_src[k * ETOT + j];
        float ev = el[(k * NN + src) * BTH + bth] + erv;
        ev = ev > 0.f ? ev : ev * 0.2f;
        s += __expf(ev - m);
    }
    emax[(k * NN + n) * BTH + bth] = m;
    inv_denom[(k * NN + n) * BTH + bth] = 1.0f / s;
}

// ---------------- Pass D: aggregate + weighted sum + merge + residual -------
__global__ __launch_bounds__(128) void agg_merge_kernel(
    const float* __restrict__ feat, const float* __restrict__ el,
    const float* __restrict__ er, const float* __restrict__ emax,
    const float* __restrict__ inv_denom,
    const int* __restrict__ row_start, const int* __restrict__ csr_src,
    const float* __restrict__ gat_bias, const float* __restrict__ weight,
    const float* __restrict__ merge_w, const float* __restrict__ merge_b,
    const float* __restrict__ x, float* __restrict__ out)
{
    int idx = blockIdx.x;
    int n = idx / BT, bt = idx - n * BT;
    int e = threadIdx.x;          // 0..127
    int h = e >> 6;
    int bth = bt * HH + h;

    float acc = 0.f;
    for (int k = 0; k < KK; ++k) {
        int s0 = row_start[k * (NN + 1) + n];
        int s1 = row_start[k * (NN + 1) + n + 1];
        float erv = er[(k * NN + n) * BTH + bth];
        float m   = emax[(k * NN + n) * BTH + bth];
        float inv = inv_denom[(k * NN + n) * BTH + bth];
        float r = 0.f;
        for (int j = s0; j < s1; ++j) {
            int src = csr_src[k * ETOT + j];
            float ev = el[(k * NN + src) * BTH + bth] + erv;
            ev = ev > 0.f ? ev : ev * 0.2f;
            float a = __expf(ev - m);
            r = fmaf(a, feat[(((size_t)(k * NN + src)) * BT + bt) * HD + e], r);
        }
        r *= inv;
        acc = fmaf(weight[k], r + gat_bias[k * HD + e], acc);
    }

    __shared__ float row[HD];
    row[e] = acc;
    __syncthreads();

    if (e < DD) {
        float mg = merge_b[e];
        #pragma unroll
        for (int q = 0; q < HD; ++q) mg = fmaf(row[q], merge_w[q * DD + e], mg);
        mg = mg > 0.f ? mg : mg * 0.01f;
        int b = bt / TT, t = bt - b * TT;
        size_t oidx = (((size_t)b * NN + n) * TT + t) * DD + e;
        out[oidx] = mg + x[oidx];   // residual: x layout [B,N,T,C], C==D
    }
}

extern "C" void kernel_launch(void* const* d_in, const int* in_sizes, int n_in,
                              void* d_out, int out_size, void* d_ws, size_t ws_size,
                              hipStream_t stream)
{
    const float* x        = (const float*)d_in[0];
    const float* fc_w     = (const float*)d_in[1];
    const float* attn_l   = (const float*)d_in[2];
    const float* attn_r   = (const float*)d_in[3];
    const float* gat_bias = (const float*)d_in[4];
    const float* weight   = (const float*)d_in[5];
    const float* merge_w  = (const float*)d_in[6];
    const float* merge_b  = (const float*)d_in[7];
    const int*   src_idx  = (const int*)d_in[8];
    const int*   dst_idx  = (const int*)d_in[9];
    float*       out      = (float*)d_out;

    // workspace carve-up (16B aligned)
    char* p = (char*)d_ws;
    auto carve = [&](size_t bytes) { char* r = p; p += (bytes + 15) & ~size_t(15); return r; };
    float* feat      = (float*)carve(sizeof(float) * (size_t)KK * NN * BT * HD);   // 75.5 MB
    float* el        = (float*)carve(sizeof(float) * KK * NN * BTH);
    float* er        = (float*)carve(sizeof(float) * KK * NN * BTH);
    float* emax      = (float*)carve(sizeof(float) * KK * NN * BTH);
    float* inv_denom = (float*)carve(sizeof(float) * KK * NN * BTH);
    int*   counts    = (int*)carve(sizeof(int) * KK * NN);
    int*   cursor    = (int*)carve(sizeof(int) * KK * NN);
    int*   row_start = (int*)carve(sizeof(int) * KK * (NN + 1));
    int*   csr_src   = (int*)carve(sizeof(int) * KK * ETOT);

    hipMemsetAsync(counts, 0, sizeof(int) * KK * NN, stream);

    feat_kernel<<<KK * NN, 128, 0, stream>>>(x, fc_w, attn_l, attn_r, feat, el, er);

    int nEdgeThreads = KK * ETOT;
    int edgeBlocks = (nEdgeThreads + 255) / 256;
    count_kernel<<<edgeBlocks, 256, 0, stream>>>(dst_idx, counts);
    scan_kernel<<<KK, 1024, 0, stream>>>(counts, row_start, cursor);
    scatter_kernel<<<edgeBlocks, 256, 0, stream>>>(src_idx, dst_idx, cursor, csr_src);

    attn_kernel<<<KK * NN, 128, 0, stream>>>(el, er, row_start, csr_src, emax, inv_denom);

    agg_merge_kernel<<<NN * BT, 128, 0, stream>>>(
        feat, el, er, emax, inv_denom, row_start, csr_src,
        gat_bias, weight, merge_w, merge_b, x, out);
}

// Round 2
// 379.791 us; speedup vs baseline: 1.2129x; 1.2129x over previous
//
#include <hip/hip_runtime.h>

#define NN   1024
#define TT   12
#define CC   64
#define DD   64
#define HH   2
#define KK   3
#define ETOT 17408           // E (16384) + N self loops
#define BT   48              // B*T
#define BTH  96              // B*T*H
#define HD   128             // H*D
#define NBTG 12              // BT/4

__device__ __forceinline__ float bf2f(unsigned short u) {
    return __uint_as_float(((unsigned int)u) << 16);
}
__device__ __forceinline__ unsigned short f2bf(float f) {
    unsigned int u = __float_as_uint(f);
    u += 0x7FFFu + ((u >> 16) & 1u);      // round-to-nearest-even
    return (unsigned short)(u >> 16);
}

// ---------------- Pass A: feat = x @ fc_w (bf16 packed), plus el/er ---------
// featp layout: [K,N,NBTG, HD*4] bf16 where element (e*4+i) = feat[bt=btg*4+i][e]
// el/er layout: [K,N, h*BT+bt]
__global__ __launch_bounds__(128) void feat_kernel(
    const float* __restrict__ x,       // [B,N,T,C]
    const float* __restrict__ fc_w,    // [K,C,HD]
    const float* __restrict__ attn_l,  // [K,H,D]
    const float* __restrict__ attn_r,  // [K,H,D]
    unsigned short* __restrict__ featp,
    float* __restrict__ el,
    float* __restrict__ er)
{
    int k = blockIdx.x / NN;
    int n = blockIdx.x % NN;
    int e = threadIdx.x;          // 0..127 (= h*64 + d)
    int h = e >> 6, d = e & 63;

    __shared__ float w_lds[CC * HD];   // 32 KB
    __shared__ float x_lds[BT * CC];   // 12 KB

    for (int i = e; i < CC * HD; i += 128) w_lds[i] = fc_w[k * CC * HD + i];
    for (int i = e; i < BT * CC; i += 128) {
        int bt = i >> 6, c = i & 63;
        int b = bt / TT, t = bt - b * TT;
        x_lds[i] = x[(((size_t)b * NN + n) * TT + t) * CC + c];
    }
    __syncthreads();

    float al = attn_l[k * HD + e];
    float ar = attn_r[k * HD + e];

    for (int btg = 0; btg < NBTG; ++btg) {
        float f4[4];
        #pragma unroll
        for (int i = 0; i < 4; ++i) {
            int bt = btg * 4 + i;
            const float* xr = &x_lds[bt * CC];
            float f = 0.f;
            #pragma unroll
            for (int c4 = 0; c4 < CC / 4; ++c4) {
                float4 xv = *(const float4*)&xr[c4 * 4];
                f = fmaf(xv.x, w_lds[(c4 * 4 + 0) * HD + e], f);
                f = fmaf(xv.y, w_lds[(c4 * 4 + 1) * HD + e], f);
                f = fmaf(xv.z, w_lds[(c4 * 4 + 2) * HD + e], f);
                f = fmaf(xv.w, w_lds[(c4 * 4 + 3) * HD + e], f);
            }
            f4[i] = f;
            float pl = f * al, pr = f * ar;
            #pragma unroll
            for (int off = 32; off > 0; off >>= 1) {
                pl += __shfl_down(pl, off, 64);
                pr += __shfl_down(pr, off, 64);
            }
            if (d == 0) {
                el[(k * NN + n) * BTH + h * BT + bt] = pl;
                er[(k * NN + n) * BTH + h * BT + bt] = pr;
            }
        }
        ushort4 pk;
        pk.x = f2bf(f4[0]); pk.y = f2bf(f4[1]); pk.z = f2bf(f4[2]); pk.w = f2bf(f4[3]);
        *(ushort4*)&featp[((size_t)((k * NN + n) * NBTG + btg) << 9) + (e << 2)] = pk;
    }
}

// ---------------- CSR build -------------------------------------------------
__global__ void count_kernel(const int* __restrict__ dst_idx, int* __restrict__ counts)
{
    int tid = blockIdx.x * blockDim.x + threadIdx.x;
    if (tid < KK * ETOT) {
        int k = tid / ETOT;
        atomicAdd(&counts[k * NN + dst_idx[tid]], 1);
    }
}

__global__ __launch_bounds__(1024) void scan_kernel(
    const int* __restrict__ counts, int* __restrict__ row_start, int* __restrict__ cursor)
{
    int k = blockIdx.x;
    int n = threadIdx.x;
    __shared__ int buf[NN];
    int my = counts[k * NN + n];
    buf[n] = my;
    __syncthreads();
    for (int off = 1; off < NN; off <<= 1) {
        int v = (n >= off) ? buf[n - off] : 0;
        __syncthreads();
        buf[n] += v;
        __syncthreads();
    }
    int incl = buf[n];
    int excl = incl - my;
    row_start[k * (NN + 1) + n] = excl;
    cursor[k * NN + n] = excl;
    if (n == NN - 1) row_start[k * (NN + 1) + NN] = incl;
}

__global__ void scatter_kernel(const int* __restrict__ src_idx,
                               const int* __restrict__ dst_idx,
                               int* __restrict__ cursor, int* __restrict__ csr_src)
{
    int tid = blockIdx.x * blockDim.x + threadIdx.x;
    if (tid < KK * ETOT) {
        int k = tid / ETOT;
        int pos = atomicAdd(&cursor[k * NN + dst_idx[tid]], 1);
        csr_src[k * ETOT + pos] = src_idx[tid];
    }
}

// ---------------- Pass C: segment softmax -> normalized alpha ---------------
// alpha layout: [K, ETOT(csr order), BTH] f32
__global__ __launch_bounds__(128) void attn_kernel(
    const float* __restrict__ el, const float* __restrict__ er,
    const int* __restrict__ row_start, const int* __restrict__ csr_src,
    float* __restrict__ alpha)
{
    int k = blockIdx.x / NN, n = blockIdx.x % NN;
    int bth = threadIdx.x;
    if (bth >= BTH) return;
    int s0 = row_start[k * (NN + 1) + n];
    int s1 = row_start[k * (NN + 1) + n + 1];
    float erv = er[(k * NN + n) * BTH + bth];

    float m = -1e30f;
    for (int j = s0; j < s1; ++j) {
        int src = csr_src[k * ETOT + j];
        float ev = el[(k * NN + src) * BTH + bth] + erv;
        ev = ev > 0.f ? ev : ev * 0.2f;
        m = fmaxf(m, ev);
    }
    float s = 0.f;
    for (int j = s0; j < s1; ++j) {
        int src = csr_src[k * ETOT + j];
        float ev = el[(k * NN + src) * BTH + bth] + erv;
        ev = ev > 0.f ? ev : ev * 0.2f;
        s += __expf(ev - m);
    }
    float inv = 1.0f / s;
    for (int j = s0; j < s1; ++j) {
        int src = csr_src[k * ETOT + j];
        float ev = el[(k * NN + src) * BTH + bth] + erv;
        ev = ev > 0.f ? ev : ev * 0.2f;
        alpha[(size_t)(k * ETOT + j) * BTH + bth] = __expf(ev - m) * inv;
    }
}

// ---------------- Pass D: aggregate (4 bt/block) + merge + residual ---------
__global__ __launch_bounds__(128) void agg_merge_kernel(
    const unsigned short* __restrict__ featp,
    const float* __restrict__ alpha,
    const int* __restrict__ row_start, const int* __restrict__ csr_src,
    const float* __restrict__ gat_bias, const float* __restrict__ weight,
    const float* __restrict__ merge_w, const float* __restrict__ merge_b,
    const float* __restrict__ x, float* __restrict__ out)
{
    int btg = blockIdx.x >> 10;        // btg-major: co-resident blocks share feat slice
    int n   = blockIdx.x & 1023;
    int e = threadIdx.x;               // 0..127
    int h = e >> 6;

    float acc0 = 0.f, acc1 = 0.f, acc2 = 0.f, acc3 = 0.f;

    for (int k = 0; k < KK; ++k) {
        int s0 = row_start[k * (NN + 1) + n];
        int s1 = row_start[k * (NN + 1) + n + 1];
        const int* csp = &csr_src[k * ETOT];
        const float* alp = &alpha[(size_t)k * ETOT * BTH + h * BT + btg * 4];
        size_t fbase = (size_t)(k * NN) * (NBTG << 9) + (btg << 9) + (e << 2);

        float r0 = 0.f, r1 = 0.f, r2 = 0.f, r3 = 0.f;
        int src_next = csp[s0];        // csr_src padded: safe even when s0==s1
        for (int j = s0; j < s1; ++j) {
            int src = src_next;
            src_next = csp[j + 1];     // prefetch (padded tail)
            float4 a4 = *(const float4*)&alp[(size_t)j * BTH];
            ushort4 fv = *(const ushort4*)&featp[fbase + ((size_t)src * (NBTG << 9))];
            r0 = fmaf(a4.x, bf2f(fv.x), r0);
            r1 = fmaf(a4.y, bf2f(fv.y), r1);
            r2 = fmaf(a4.z, bf2f(fv.z), r2);
            r3 = fmaf(a4.w, bf2f(fv.w), r3);
        }
        float wk = weight[k];
        float bias = gat_bias[k * HD + e];
        acc0 = fmaf(wk, r0 + bias, acc0);
        acc1 = fmaf(wk, r1 + bias, acc1);
        acc2 = fmaf(wk, r2 + bias, acc2);
        acc3 = fmaf(wk, r3 + bias, acc3);
    }

    __shared__ float rows[4][HD];      // 2 KB
    rows[0][e] = acc0; rows[1][e] = acc1; rows[2][e] = acc2; rows[3][e] = acc3;
    __syncthreads();

    #pragma unroll
    for (int pass = 0; pass < 2; ++pass) {
        int oi = pass * 128 + e;       // 256 outputs: 4 rows x 64 cols
        int rr = oi >> 6, dd = oi & 63;
        float mg = merge_b[dd];
        #pragma unroll
        for (int q = 0; q < HD; ++q) mg = fmaf(rows[rr][q], merge_w[q * DD + dd], mg);
        mg = mg > 0.f ? mg : mg * 0.01f;
        int bt = btg * 4 + rr;
        int b = bt / TT, t = bt - b * TT;
        size_t oidx = (((size_t)b * NN + n) * TT + t) * DD + dd;
        out[oidx] = mg + x[oidx];
    }
}

extern "C" void kernel_launch(void* const* d_in, const int* in_sizes, int n_in,
                              void* d_out, int out_size, void* d_ws, size_t ws_size,
                              hipStream_t stream)
{
    const float* x        = (const float*)d_in[0];
    const float* fc_w     = (const float*)d_in[1];
    const float* attn_l   = (const float*)d_in[2];
    const float* attn_r   = (const float*)d_in[3];
    const float* gat_bias = (const float*)d_in[4];
    const float* weight   = (const float*)d_in[5];
    const float* merge_w  = (const float*)d_in[6];
    const float* merge_b  = (const float*)d_in[7];
    const int*   src_idx  = (const int*)d_in[8];
    const int*   dst_idx  = (const int*)d_in[9];
    float*       out      = (float*)d_out;

    char* p = (char*)d_ws;
    auto carve = [&](size_t bytes) { char* r = p; p += (bytes + 15) & ~size_t(15); return r; };
    unsigned short* featp = (unsigned short*)carve(sizeof(unsigned short) * (size_t)KK * NN * BT * HD); // 37.7 MB
    float* el        = (float*)carve(sizeof(float) * KK * NN * BTH);
    float* er        = (float*)carve(sizeof(float) * KK * NN * BTH);
    float* alpha     = (float*)carve(sizeof(float) * (size_t)KK * ETOT * BTH);                          // 20.1 MB
    int*   counts    = (int*)carve(sizeof(int) * KK * NN);
    int*   cursor    = (int*)carve(sizeof(int) * KK * NN);
    int*   row_start = (int*)carve(sizeof(int) * KK * (NN + 1));
    int*   csr_src   = (int*)carve(sizeof(int) * (KK * ETOT + 16));  // +pad for prefetch

    hipMemsetAsync(counts, 0, sizeof(int) * KK * NN, stream);

    feat_kernel<<<KK * NN, 128, 0, stream>>>(x, fc_w, attn_l, attn_r, featp, el, er);

    int edgeBlocks = (KK * ETOT + 255) / 256;
    count_kernel<<<edgeBlocks, 256, 0, stream>>>(dst_idx, counts);
    scan_kernel<<<KK, 1024, 0, stream>>>(counts, row_start, cursor);
    scatter_kernel<<<edgeBlocks, 256, 0, stream>>>(src_idx, dst_idx, cursor, csr_src);

    attn_kernel<<<KK * NN, 128, 0, stream>>>(el, er, row_start, csr_src, alpha);

    agg_merge_kernel<<<NN * NBTG, 128, 0, stream>>>(
        featp, alpha, row_start, csr_src,
        gat_bias, weight, merge_w, merge_b, x, out);
}

// Round 3
// 218.895 us; speedup vs baseline: 2.1045x; 1.7350x over previous
//
#include <hip/hip_runtime.h>

#define NN   1024
#define TT   12
#define CC   64
#define DD   64
#define HH   2
#define KK   3
#define ETOT 17408           // E (16384) + N self loops
#define BT   48              // B*T
#define BTH  96              // B*T*H
#define HD   128             // H*D
#define NBTG 6               // BT/8  (8 bt per block)

__device__ __forceinline__ float bf_lo(unsigned int u) {
    return __uint_as_float(u << 16);
}
__device__ __forceinline__ float bf_hi(unsigned int u) {
    return __uint_as_float(u & 0xFFFF0000u);
}
__device__ __forceinline__ unsigned short f2bf(float f) {
    unsigned int u = __float_as_uint(f);
    u += 0x7FFFu + ((u >> 16) & 1u);      // round-to-nearest-even
    return (unsigned short)(u >> 16);
}
__device__ __forceinline__ unsigned int pack2(float a, float b) {
    return (unsigned int)f2bf(a) | ((unsigned int)f2bf(b) << 16);
}

// ---------------- Pass A: feat = x @ fc_w (bf16 packed), plus el/er ---------
// featp (as uint4): [K,N,NBTG] chunks of 128 uint4; lane e's uint4 packs
//   feat[bt = btg*8 + 0..7][e]  (lo/hi bf16 pairs)
// el/er layout: [K,N, h*BT+bt]
__global__ __launch_bounds__(128) void feat_kernel(
    const float* __restrict__ x,       // [B,N,T,C]
    const float* __restrict__ fc_w,    // [K,C,HD]
    const float* __restrict__ attn_l,  // [K,H,D]
    const float* __restrict__ attn_r,  // [K,H,D]
    uint4* __restrict__ featp,
    float* __restrict__ el,
    float* __restrict__ er)
{
    int k = blockIdx.x / NN;
    int n = blockIdx.x % NN;
    int e = threadIdx.x;          // 0..127 (= h*64 + d)
    int h = e >> 6, d = e & 63;

    __shared__ float x_lds[BT * CC];   // 12 KB

    // W column e in registers
    float wreg[CC];
    #pragma unroll
    for (int c = 0; c < CC; ++c) wreg[c] = fc_w[k * CC * HD + c * HD + e];

    for (int i = e; i < BT * CC; i += 128) {
        int bt = i >> 6, c = i & 63;
        int b = bt / TT, t = bt - b * TT;
        x_lds[i] = x[(((size_t)b * NN + n) * TT + t) * CC + c];
    }
    __syncthreads();

    float al = attn_l[k * HD + e];
    float ar = attn_r[k * HD + e];

    for (int btg = 0; btg < NBTG; ++btg) {
        float f8[8];
        #pragma unroll
        for (int i = 0; i < 8; ++i) {
            int bt = btg * 8 + i;
            const float* xr = &x_lds[bt * CC];
            float f = 0.f;
            #pragma unroll
            for (int c4 = 0; c4 < CC / 4; ++c4) {
                float4 xv = *(const float4*)&xr[c4 * 4];
                f = fmaf(xv.x, wreg[c4 * 4 + 0], f);
                f = fmaf(xv.y, wreg[c4 * 4 + 1], f);
                f = fmaf(xv.z, wreg[c4 * 4 + 2], f);
                f = fmaf(xv.w, wreg[c4 * 4 + 3], f);
            }
            f8[i] = f;
            float pl = f * al, pr = f * ar;
            #pragma unroll
            for (int off = 32; off > 0; off >>= 1) {
                pl += __shfl_down(pl, off, 64);
                pr += __shfl_down(pr, off, 64);
            }
            if (d == 0) {
                el[(k * NN + n) * BTH + h * BT + bt] = pl;
                er[(k * NN + n) * BTH + h * BT + bt] = pr;
            }
        }
        uint4 pk;
        pk.x = pack2(f8[0], f8[1]);
        pk.y = pack2(f8[2], f8[3]);
        pk.z = pack2(f8[4], f8[5]);
        pk.w = pack2(f8[6], f8[7]);
        featp[(size_t)((k * NN + n) * NBTG + btg) * 128 + e] = pk;
    }
}

// ---------------- CSR build -------------------------------------------------
__global__ void count_kernel(const int* __restrict__ dst_idx, int* __restrict__ counts)
{
    int tid = blockIdx.x * blockDim.x + threadIdx.x;
    if (tid < KK * ETOT) {
        int k = tid / ETOT;
        atomicAdd(&counts[k * NN + dst_idx[tid]], 1);
    }
}

__global__ __launch_bounds__(1024) void scan_kernel(
    const int* __restrict__ counts, int* __restrict__ row_start, int* __restrict__ cursor)
{
    int k = blockIdx.x;
    int n = threadIdx.x;
    __shared__ int buf[NN];
    int my = counts[k * NN + n];
    buf[n] = my;
    __syncthreads();
    for (int off = 1; off < NN; off <<= 1) {
        int v = (n >= off) ? buf[n - off] : 0;
        __syncthreads();
        buf[n] += v;
        __syncthreads();
    }
    int incl = buf[n];
    int excl = incl - my;
    row_start[k * (NN + 1) + n] = excl;
    cursor[k * NN + n] = excl;
    if (n == NN - 1) row_start[k * (NN + 1) + NN] = incl;
}

__global__ void scatter_kernel(const int* __restrict__ src_idx,
                               const int* __restrict__ dst_idx,
                               int* __restrict__ cursor, int* __restrict__ csr_src)
{
    int tid = blockIdx.x * blockDim.x + threadIdx.x;
    if (tid < KK * ETOT) {
        int k = tid / ETOT;
        int pos = atomicAdd(&cursor[k * NN + dst_idx[tid]], 1);
        csr_src[k * ETOT + pos] = src_idx[tid];
    }
}

// ---------------- Pass C: softmax, single pass (no max-shift needed) --------
// alpha[(k*ETOT+j)*BTH + bth] = exp(lrelu(el[src]+er[n]))   (unnormalized)
// inv_denom[(k*NN+n)*BTH + bth] = 1/sum
__global__ __launch_bounds__(128) void attn_kernel(
    const float* __restrict__ el, const float* __restrict__ er,
    const int* __restrict__ row_start, const int* __restrict__ csr_src,
    float* __restrict__ alpha, float* __restrict__ inv_denom)
{
    int k = blockIdx.x / NN, n = blockIdx.x % NN;
    int bth = threadIdx.x;
    if (bth >= BTH) return;
    int s0 = row_start[k * (NN + 1) + n];
    int s1 = row_start[k * (NN + 1) + n + 1];
    const int* csp = &csr_src[k * ETOT];
    float erv = er[(k * NN + n) * BTH + bth];

    float s = 0.f;
    int j = s0;
    for (; j + 4 <= s1; j += 4) {
        int sa = csp[j], sb = csp[j + 1], sc = csp[j + 2], sd = csp[j + 3];
        float ea = el[(k * NN + sa) * BTH + bth] + erv;
        float eb = el[(k * NN + sb) * BTH + bth] + erv;
        float ec = el[(k * NN + sc) * BTH + bth] + erv;
        float ed = el[(k * NN + sd) * BTH + bth] + erv;
        ea = ea > 0.f ? ea : ea * 0.2f;  eb = eb > 0.f ? eb : eb * 0.2f;
        ec = ec > 0.f ? ec : ec * 0.2f;  ed = ed > 0.f ? ed : ed * 0.2f;
        float aa = __expf(ea), ab = __expf(eb), ac = __expf(ec), ad = __expf(ed);
        alpha[(size_t)(k * ETOT + j + 0) * BTH + bth] = aa;
        alpha[(size_t)(k * ETOT + j + 1) * BTH + bth] = ab;
        alpha[(size_t)(k * ETOT + j + 2) * BTH + bth] = ac;
        alpha[(size_t)(k * ETOT + j + 3) * BTH + bth] = ad;
        s += (aa + ab) + (ac + ad);
    }
    for (; j < s1; ++j) {
        int src = csp[j];
        float ev = el[(k * NN + src) * BTH + bth] + erv;
        ev = ev > 0.f ? ev : ev * 0.2f;
        float a = __expf(ev);
        alpha[(size_t)(k * ETOT + j) * BTH + bth] = a;
        s += a;
    }
    inv_denom[(k * NN + n) * BTH + bth] = 1.0f / s;
}

// ---------------- Pass D: aggregate (8 bt/block, unroll 4) + merge ----------
__global__ __launch_bounds__(128) void agg_merge_kernel(
    const uint4* __restrict__ featp,
    const float* __restrict__ alpha,
    const float* __restrict__ inv_denom,
    const int* __restrict__ row_start, const int* __restrict__ csr_src,
    const float* __restrict__ gat_bias, const float* __restrict__ weight,
    const float* __restrict__ merge_w, const float* __restrict__ merge_b,
    const float* __restrict__ x, float* __restrict__ out)
{
    int btg = blockIdx.x / NN;       // btg-major: co-resident blocks share feat slice
    int n   = blockIdx.x - btg * NN;
    int e = threadIdx.x;             // 0..127
    int h = e >> 6;

    float acc[8];
    #pragma unroll
    for (int i = 0; i < 8; ++i) acc[i] = 0.f;

    for (int k = 0; k < KK; ++k) {
        int s0 = row_start[k * (NN + 1) + n];
        int s1 = row_start[k * (NN + 1) + n + 1];
        const int* csp = &csr_src[k * ETOT];
        const float* alp = &alpha[(size_t)k * ETOT * BTH + h * BT + btg * 8];
        const uint4* fb = featp + (size_t)(k * NN * NBTG + btg) * 128 + e;

        float r[8];
        #pragma unroll
        for (int i = 0; i < 8; ++i) r[i] = 0.f;

        int j = s0;
        for (; j + 4 <= s1; j += 4) {
            int sa = csp[j], sb = csp[j + 1], sc = csp[j + 2], sd = csp[j + 3];
            uint4 f0 = fb[(size_t)sa * (NBTG * 128)];
            uint4 f1 = fb[(size_t)sb * (NBTG * 128)];
            uint4 f2 = fb[(size_t)sc * (NBTG * 128)];
            uint4 f3 = fb[(size_t)sd * (NBTG * 128)];
            float4 A0 = *(const float4*)&alp[(size_t)(j + 0) * BTH];
            float4 B0 = *(const float4*)&alp[(size_t)(j + 0) * BTH + 4];
            float4 A1 = *(const float4*)&alp[(size_t)(j + 1) * BTH];
            float4 B1 = *(const float4*)&alp[(size_t)(j + 1) * BTH + 4];
            float4 A2 = *(const float4*)&alp[(size_t)(j + 2) * BTH];
            float4 B2 = *(const float4*)&alp[(size_t)(j + 2) * BTH + 4];
            float4 A3 = *(const float4*)&alp[(size_t)(j + 3) * BTH];
            float4 B3 = *(const float4*)&alp[(size_t)(j + 3) * BTH + 4];

            r[0] = fmaf(A0.x, bf_lo(f0.x), r[0]); r[1] = fmaf(A0.y, bf_hi(f0.x), r[1]);
            r[2] = fmaf(A0.z, bf_lo(f0.y), r[2]); r[3] = fmaf(A0.w, bf_hi(f0.y), r[3]);
            r[4] = fmaf(B0.x, bf_lo(f0.z), r[4]); r[5] = fmaf(B0.y, bf_hi(f0.z), r[5]);
            r[6] = fmaf(B0.z, bf_lo(f0.w), r[6]); r[7] = fmaf(B0.w, bf_hi(f0.w), r[7]);

            r[0] = fmaf(A1.x, bf_lo(f1.x), r[0]); r[1] = fmaf(A1.y, bf_hi(f1.x), r[1]);
            r[2] = fmaf(A1.z, bf_lo(f1.y), r[2]); r[3] = fmaf(A1.w, bf_hi(f1.y), r[3]);
            r[4] = fmaf(B1.x, bf_lo(f1.z), r[4]); r[5] = fmaf(B1.y, bf_hi(f1.z), r[5]);
            r[6] = fmaf(B1.z, bf_lo(f1.w), r[6]); r[7] = fmaf(B1.w, bf_hi(f1.w), r[7]);

            r[0] = fmaf(A2.x, bf_lo(f2.x), r[0]); r[1] = fmaf(A2.y, bf_hi(f2.x), r[1]);
            r[2] = fmaf(A2.z, bf_lo(f2.y), r[2]); r[3] = fmaf(A2.w, bf_hi(f2.y), r[3]);
            r[4] = fmaf(B2.x, bf_lo(f2.z), r[4]); r[5] = fmaf(B2.y, bf_hi(f2.z), r[5]);
            r[6] = fmaf(B2.z, bf_lo(f2.w), r[6]); r[7] = fmaf(B2.w, bf_hi(f2.w), r[7]);

            r[0] = fmaf(A3.x, bf_lo(f3.x), r[0]); r[1] = fmaf(A3.y, bf_hi(f3.x), r[1]);
            r[2] = fmaf(A3.z, bf_lo(f3.y), r[2]); r[3] = fmaf(A3.w, bf_hi(f3.y), r[3]);
            r[4] = fmaf(B3.x, bf_lo(f3.z), r[4]); r[5] = fmaf(B3.y, bf_hi(f3.z), r[5]);
            r[6] = fmaf(B3.z, bf_lo(f3.w), r[6]); r[7] = fmaf(B3.w, bf_hi(f3.w), r[7]);
        }
        for (; j < s1; ++j) {
            int src = csp[j];
            uint4 f0 = fb[(size_t)src * (NBTG * 128)];
            float4 A0 = *(const float4*)&alp[(size_t)j * BTH];
            float4 B0 = *(const float4*)&alp[(size_t)j * BTH + 4];
            r[0] = fmaf(A0.x, bf_lo(f0.x), r[0]); r[1] = fmaf(A0.y, bf_hi(f0.x), r[1]);
            r[2] = fmaf(A0.z, bf_lo(f0.y), r[2]); r[3] = fmaf(A0.w, bf_hi(f0.y), r[3]);
            r[4] = fmaf(B0.x, bf_lo(f0.z), r[4]); r[5] = fmaf(B0.y, bf_hi(f0.z), r[5]);
            r[6] = fmaf(B0.z, bf_lo(f0.w), r[6]); r[7] = fmaf(B0.w, bf_hi(f0.w), r[7]);
        }

        const float* ivp = &inv_denom[(size_t)(k * NN + n) * BTH + h * BT + btg * 8];
        float4 ivA = *(const float4*)&ivp[0];
        float4 ivB = *(const float4*)&ivp[4];
        float wk = weight[k];
        float bias = gat_bias[k * HD + e];
        acc[0] = fmaf(wk, fmaf(r[0], ivA.x, bias), acc[0]);
        acc[1] = fmaf(wk, fmaf(r[1], ivA.y, bias), acc[1]);
        acc[2] = fmaf(wk, fmaf(r[2], ivA.z, bias), acc[2]);
        acc[3] = fmaf(wk, fmaf(r[3], ivA.w, bias), acc[3]);
        acc[4] = fmaf(wk, fmaf(r[4], ivB.x, bias), acc[4]);
        acc[5] = fmaf(wk, fmaf(r[5], ivB.y, bias), acc[5]);
        acc[6] = fmaf(wk, fmaf(r[6], ivB.z, bias), acc[6]);
        acc[7] = fmaf(wk, fmaf(r[7], ivB.w, bias), acc[7]);
    }

    __shared__ float rows[8][HD];      // 4 KB
    #pragma unroll
    for (int i = 0; i < 8; ++i) rows[i][e] = acc[i];
    __syncthreads();

    #pragma unroll
    for (int pass = 0; pass < 4; ++pass) {
        int oi = pass * 128 + e;       // 512 outputs: 8 rows x 64 cols
        int rr = oi >> 6, dd = oi & 63;
        float mg = merge_b[dd];
        #pragma unroll
        for (int q = 0; q < HD; ++q) mg = fmaf(rows[rr][q], merge_w[q * DD + dd], mg);
        mg = mg > 0.f ? mg : mg * 0.01f;
        int bt = btg * 8 + rr;
        int b = bt / TT, t = bt - b * TT;
        size_t oidx = (((size_t)b * NN + n) * TT + t) * DD + dd;
        out[oidx] = mg + x[oidx];
    }
}

extern "C" void kernel_launch(void* const* d_in, const int* in_sizes, int n_in,
                              void* d_out, int out_size, void* d_ws, size_t ws_size,
                              hipStream_t stream)
{
    const float* x        = (const float*)d_in[0];
    const float* fc_w     = (const float*)d_in[1];
    const float* attn_l   = (const float*)d_in[2];
    const float* attn_r   = (const float*)d_in[3];
    const float* gat_bias = (const float*)d_in[4];
    const float* weight   = (const float*)d_in[5];
    const float* merge_w  = (const float*)d_in[6];
    const float* merge_b  = (const float*)d_in[7];
    const int*   src_idx  = (const int*)d_in[8];
    const int*   dst_idx  = (const int*)d_in[9];
    float*       out      = (float*)d_out;

    char* p = (char*)d_ws;
    auto carve = [&](size_t bytes) { char* r = p; p += (bytes + 15) & ~size_t(15); return r; };
    uint4* featp     = (uint4*)carve(sizeof(unsigned short) * (size_t)KK * NN * BT * HD); // 37.7 MB
    float* el        = (float*)carve(sizeof(float) * KK * NN * BTH);
    float* er        = (float*)carve(sizeof(float) * KK * NN * BTH);
    float* alpha     = (float*)carve(sizeof(float) * (size_t)KK * ETOT * BTH);            // 20.1 MB
    float* inv_denom = (float*)carve(sizeof(float) * KK * NN * BTH);
    int*   counts    = (int*)carve(sizeof(int) * KK * NN);
    int*   cursor    = (int*)carve(sizeof(int) * KK * NN);
    int*   row_start = (int*)carve(sizeof(int) * KK * (NN + 1));
    int*   csr_src   = (int*)carve(sizeof(int) * (KK * ETOT + 16));

    hipMemsetAsync(counts, 0, sizeof(int) * KK * NN, stream);

    feat_kernel<<<KK * NN, 128, 0, stream>>>(x, fc_w, attn_l, attn_r, featp, el, er);

    int edgeBlocks = (KK * ETOT + 255) / 256;
    count_kernel<<<edgeBlocks, 256, 0, stream>>>(dst_idx, counts);
    scan_kernel<<<KK, 1024, 0, stream>>>(counts, row_start, cursor);
    scatter_kernel<<<edgeBlocks, 256, 0, stream>>>(src_idx, dst_idx, cursor, csr_src);

    attn_kernel<<<KK * NN, 128, 0, stream>>>(el, er, row_start, csr_src, alpha, inv_denom);

    agg_merge_kernel<<<NN * NBTG, 128, 0, stream>>>(
        featp, alpha, inv_denom, row_start, csr_src,
        gat_bias, weight, merge_w, merge_b, x, out);
}